// Round 9
// baseline (276.717 us; speedup 1.0000x reference)
//
#include <hip/hip_runtime.h>

typedef __attribute__((ext_vector_type(4))) float f32x4;
typedef __attribute__((ext_vector_type(16))) float f32x16;
typedef __attribute__((ext_vector_type(8))) short short8;
typedef __attribute__((ext_vector_type(4))) unsigned short us4;
typedef unsigned short u16;
typedef unsigned int u32;
typedef _Float16 f16;
typedef __attribute__((ext_vector_type(8))) f16 f16x8;
typedef __attribute__((ext_vector_type(2))) __fp16 fp16x2;

#define B_   16
#define N_   2048
#define C_   256
#define CIN  131
#define COUT 128
#define L2E  1.44269504088896f

__device__ __forceinline__ u16 f2bf(float x) {
    u32 u = __float_as_uint(x);
    u32 r = (u + 0x7fffu + ((u >> 16) & 1u)) >> 16;
    return (u16)r;
}
__device__ __forceinline__ float bf2f(u16 h) {
    return __uint_as_float(((u32)h) << 16);
}
__device__ __forceinline__ u16 f2h(float x) {
    union { f16 h; u16 u; } c; c.h = (f16)x; return c.u;
}

__device__ __forceinline__ f32x4 mfma16(short8 a, short8 b, f32x4 c) {
    return __builtin_amdgcn_mfma_f32_16x16x32_bf16(a, b, c, 0, 0, 0);
}
__device__ __forceinline__ f32x4 mfma16h(f16x8 a, f16x8 b, f32x4 c) {
    return __builtin_amdgcn_mfma_f32_16x16x32_f16(a, b, c, 0, 0, 0);
}
__device__ __forceinline__ f32x16 mfma32(short8 a, short8 b, f32x16 c) {
    return __builtin_amdgcn_mfma_f32_32x32x16_bf16(a, b, c, 0, 0, 0);
}
__device__ __forceinline__ f32x16 mfma32h(f16x8 a, f16x8 b, f32x16 c) {
    return __builtin_amdgcn_mfma_f32_32x32x16_f16(a, b, c, 0, 0, 0);
}
__device__ __forceinline__ f32x16 z16() {
    f32x16 v;
    #pragma unroll
    for (int i = 0; i < 16; ++i) v[i] = 0.f;
    return v;
}
__device__ __forceinline__ u32 pkrtz(float a, float b) {
    fp16x2 r = __builtin_amdgcn_cvt_pkrtz(a, b);
    union { fp16x2 v; u32 u; } c; c.v = r; return c.u;
}
__device__ __forceinline__ float bperm_f(int lane, float v) {
    return __uint_as_float((u32)__builtin_amdgcn_ds_bpermute(lane * 4, (int)__float_as_uint(v)));
}

typedef __attribute__((address_space(1))) const unsigned int gu32;
typedef __attribute__((address_space(3))) unsigned int lu32;
__device__ __forceinline__ void gl_lds16(const u16* g, u16* l) {
    __builtin_amdgcn_global_load_lds((gu32*)g, (lu32*)l, 16, 0, 0);
}

#define RAW_BARRIER() do { asm volatile("" ::: "memory"); \
    __builtin_amdgcn_s_barrier(); \
    asm volatile("" ::: "memory"); } while (0)

// ---------------------------------------------------------------------------
// Kernel 1: weight prep (unchanged from R8).
// ---------------------------------------------------------------------------
__global__ __launch_bounds__(256) void w_prep(
    const float* __restrict__ Wq, const float* __restrict__ Wk,
    const float* __restrict__ Wv, const float* __restrict__ Wf,
    const float* __restrict__ bnq, const float* __restrict__ bnk,
    const float* __restrict__ bnv, const float* __restrict__ bnf,
    u16* __restrict__ wAh, u16* __restrict__ wAl,
    u16* __restrict__ wfh, u16* __restrict__ wfl,
    float* __restrict__ sqkv, float* __restrict__ tqkv,
    float* __restrict__ sf, float* __restrict__ tf)
{
    int t = threadIdx.x, l = t & 63;
    int g = blockIdx.x * 4 + (t >> 6);
    if (g < 240) {
        int m = g / 80, rem = g % 80, og = rem / 5, cc = rem % 5;
        const float* W = (m == 0) ? Wq : (m == 1) ? Wk : Wv;
        int o = og * 16 + (l & 15);
        size_t base = ((size_t)g * 64 + l) * 8;
        #pragma unroll
        for (int j = 0; j < 8; ++j) {
            int k = cc * 32 + (l >> 4) * 8 + j;
            float f = (k < CIN) ? W[o * CIN + k] : 0.f;
            u16 h = f2bf(f);
            wAh[base + j] = h;
            wAl[base + j] = f2bf(f - bf2f(h));
        }
    } else if (g < 304) {
        int u = g - 240;
        int o = (u >> 3) * 16 + (l & 15);
        int c0 = (u & 7) * 32 + (l >> 4) * 8;
        size_t base = ((size_t)u * 64 + l) * 8;
        #pragma unroll
        for (int j = 0; j < 8; ++j) {
            float f = Wf[o * 256 + c0 + j];
            u16 h = f2h(f);
            wfh[base + j] = h;
            union { f16 hh; u16 uu; } c; c.uu = h;
            wfl[base + j] = f2h(f - (float)c.hh);
        }
    }
    if (blockIdx.x == 0) {
        if (t < 256) {
            #pragma unroll
            for (int m = 0; m < 3; ++m) {
                const float* bn = (m == 0) ? bnq : (m == 1) ? bnk : bnv;
                float s = bn[t] * rsqrtf(bn[768 + t] + 1e-5f);
                sqkv[m * 256 + t] = s;
                tqkv[m * 256 + t] = bn[256 + t] - bn[512 + t] * s;
            }
        }
        if (t < 128) {
            float s = bnf[t] * rsqrtf(bnf[384 + t] + 1e-5f);
            sf[t] = s;
            tf[t] = bnf[128 + t] - bnf[256 + t] * s;
        }
    }
}

// ---------------------------------------------------------------------------
// Kernel 2: QKV projection via MFMA hi/lo bf16 (unchanged from R8).
// ---------------------------------------------------------------------------
__global__ __launch_bounds__(256) void qkv_proj(
    const float* __restrict__ x,
    const u16* __restrict__ wAh, const u16* __restrict__ wAl,
    const float* __restrict__ sqkv, const float* __restrict__ tqkv,
    u16* __restrict__ qh, u16* __restrict__ ql,
    u16* __restrict__ kh, u16* __restrict__ kl, u16* __restrict__ vt)
{
    __shared__ __align__(16) float xs[64][164];

    int bid = blockIdx.x;
    int m  = bid >> 9;
    int r9 = bid & 511;
    int b = r9 >> 5, nt = r9 & 31;
    int t = threadIdx.x;
    int w = t >> 6, l = t & 63;
    int n0 = nt * 64;

    {
        int nb = (t & 15) * 4;
        for (int k = (t >> 4); k < CIN; k += 16) {
            f32x4 v = *(const f32x4*)(x + ((size_t)b * CIN + k) * N_ + n0 + nb);
            xs[nb + 0][k] = v[0]; xs[nb + 1][k] = v[1];
            xs[nb + 2][k] = v[2]; xs[nb + 3][k] = v[3];
        }
        for (int idx = t; idx < 64 * 29; idx += 256) {
            int n = idx / 29, k = CIN + idx % 29;
            xs[n][k] = 0.f;
        }
    }
    __syncthreads();

    f32x4 acc[4][4];
    #pragma unroll
    for (int og = 0; og < 4; ++og)
        #pragma unroll
        for (int njg = 0; njg < 4; ++njg) acc[og][njg] = (f32x4){0.f, 0.f, 0.f, 0.f};

    for (int cc = 0; cc < 5; ++cc) {
        short8 xbh[4], xbl[4];
        #pragma unroll
        for (int njg = 0; njg < 4; ++njg) {
            int n = njg * 16 + (l & 15);
            int k0 = cc * 32 + (l >> 4) * 8;
            f32x4 u0 = *(const f32x4*)&xs[n][k0];
            f32x4 u1 = *(const f32x4*)&xs[n][k0 + 4];
            u16 hh[8], ll[8];
            #pragma unroll
            for (int jj = 0; jj < 4; ++jj) {
                hh[jj] = f2bf(u0[jj]);     ll[jj] = f2bf(u0[jj] - bf2f(hh[jj]));
                hh[4 + jj] = f2bf(u1[jj]); ll[4 + jj] = f2bf(u1[jj] - bf2f(hh[4 + jj]));
            }
            short8 vh_, vl_;
            #pragma unroll
            for (int jj = 0; jj < 8; ++jj) { vh_[jj] = (short)hh[jj]; vl_[jj] = (short)ll[jj]; }
            xbh[njg] = vh_; xbl[njg] = vl_;
        }
        #pragma unroll
        for (int og = 0; og < 4; ++og) {
            size_t base = (((size_t)(m * 16 + w * 4 + og) * 5 + cc) * 64 + l) * 8;
            short8 ah  = *(const short8*)(wAh + base);
            short8 al4 = *(const short8*)(wAl + base);
            #pragma unroll
            for (int njg = 0; njg < 4; ++njg) {
                acc[og][njg] = mfma16(ah,  xbh[njg], acc[og][njg]);
                acc[og][njg] = mfma16(ah,  xbl[njg], acc[og][njg]);
                acc[og][njg] = mfma16(al4, xbh[njg], acc[og][njg]);
            }
        }
    }

    #pragma unroll
    for (int og = 0; og < 4; ++og) {
        int cb = (w * 4 + og) * 16 + (l >> 4) * 4;
        f32x4 sv = *(const f32x4*)(sqkv + m * 256 + cb);
        f32x4 tv = *(const f32x4*)(tqkv + m * 256 + cb);
        #pragma unroll
        for (int njg = 0; njg < 4; ++njg) {
            int n = n0 + njg * 16 + (l & 15);
            float z[4];
            #pragma unroll
            for (int r = 0; r < 4; ++r)
                z[r] = fmaxf(fmaf(acc[og][njg][r], sv[r], tv[r]), 0.f);
            if (m < 2) {
                size_t base = ((((size_t)b * 64 + (n >> 5)) * 16 + (cb >> 4)) * 64
                               + ((cb >> 3) & 1) * 32 + (n & 31)) * 8 + ((cb >> 2) & 1) * 4;
                u16 h0 = f2bf(z[0]), h1 = f2bf(z[1]), h2 = f2bf(z[2]), h3 = f2bf(z[3]);
                us4 hi4 = { h0, h1, h2, h3 };
                us4 lo4 = { f2bf(z[0] - bf2f(h0)), f2bf(z[1] - bf2f(h1)),
                            f2bf(z[2] - bf2f(h2)), f2bf(z[3] - bf2f(h3)) };
                *(us4*)((m ? kh : qh) + base) = hi4;
                *(us4*)((m ? kl : ql) + base) = lo4;
            } else {
                size_t base = ((((size_t)b * 128 + (n >> 4)) * 8 + (cb >> 5)) * 64
                               + ((cb >> 3) & 3) * 16 + (n & 15)) * 8 + (cb & 7);
                us4 v0 = { f2h(z[0]), f2h(z[1]), f2h(z[2]), f2h(z[3]) };
                *(us4*)(vt + base) = v0;
            }
        }
    }
}

// ---------------------------------------------------------------------------
// Kernel 2b: VW = V^T · Wf (fp16, 32x32 B-frag layout) — unchanged from R8.
// ---------------------------------------------------------------------------
__global__ __launch_bounds__(256) void vw_proj(
    const u16* __restrict__ vt,
    const u16* __restrict__ wfh, const u16* __restrict__ wfl,
    u16* __restrict__ vw)
{
    int bid = blockIdx.x;
    int b = bid >> 4, mt = bid & 15;
    int t = threadIdx.x, w = t >> 6, l = t & 63;

    f32x4 acc[2][8];
    #pragma unroll
    for (int oi = 0; oi < 2; ++oi)
        #pragma unroll
        for (int mg = 0; mg < 8; ++mg) acc[oi][mg] = (f32x4){0.f, 0.f, 0.f, 0.f};

    for (int cc = 0; cc < 8; ++cc) {
        f16x8 vtf[8];
        #pragma unroll
        for (int mg = 0; mg < 8; ++mg)
            vtf[mg] = *(const f16x8*)(vt + ((((size_t)b * 128 + mt * 8 + mg) * 8 + cc) * 64 + l) * 8);
        #pragma unroll
        for (int oi = 0; oi < 2; ++oi) {
            int og = w * 2 + oi;
            f16x8 bh = *(const f16x8*)(wfh + (((size_t)og * 8 + cc) * 64 + l) * 8);
            f16x8 bl = *(const f16x8*)(wfl + (((size_t)og * 8 + cc) * 64 + l) * 8);
            #pragma unroll
            for (int mg = 0; mg < 8; ++mg) {
                acc[oi][mg] = mfma16h(vtf[mg], bh, acc[oi][mg]);
                acc[oi][mg] = mfma16h(vtf[mg], bl, acc[oi][mg]);
            }
        }
    }

    #pragma unroll
    for (int oi = 0; oi < 2; ++oi) {
        int og = w * 2 + oi;
        int o = og * 16 + (l & 15);
        #pragma unroll
        for (int mg = 0; mg < 8; ++mg) {
            int mm0 = mt * 128 + mg * 16 + (l >> 4) * 4;
            size_t idx = ((((size_t)b * 64 + (mm0 >> 5)) * 4 + (o >> 5)) * 2 + ((mm0 >> 4) & 1)) * 512
                         + (size_t)(((mm0 >> 3) & 1) * 32 + (o & 31)) * 8 + (mm0 & 7);
            us4 v = { f2h(acc[oi][mg][0]), f2h(acc[oi][mg][1]),
                      f2h(acc[oi][mg][2]), f2h(acc[oi][mg][3]) };
            *(us4*)(vw + idx) = v;
        }
    }
}

// ---------------------------------------------------------------------------
// Kernel 3: flash attention, intra-block split-KV pairing for 2 waves/SIMD.
// Block = 4 waves: (pair p, parity par) = (w>>1, w&1). Pair p owns q-rows
// [pt*64+p*32, +32); parity par processes KV tiles mc = 2r+par (32 rounds).
// On-chip merge at end (odd->LDS, even merges + stores).
// LDS = exactly 80KB: Keven[16384 u16]@0, Kodd@16384, VWe@32768, VWo@36864.
// Grid 512 = 2 blocks/CU -> 8 waves/CU = 2/SIMD (the round's lever).
// Rescale factor redistribution via ds_bpermute (no als buffer).
// ---------------------------------------------------------------------------
__global__ __launch_bounds__(256, 2) void attn_fwd(
    const u16* __restrict__ qh, const u16* __restrict__ ql,
    const u16* __restrict__ kh, const u16* __restrict__ kl,
    const u16* __restrict__ vw,
    const float* __restrict__ sf, const float* __restrict__ tf,
    float* __restrict__ out)
{
    __shared__ __align__(16) u16 smem[40960];   // 81920 B exactly

    int bid = blockIdx.x;
    int swz = (bid & 7) * 64 + (bid >> 3);      // XCD-chunked swizzle (512 = 8*64)
    int b   = swz >> 5;
    int pt  = swz & 31;
    int tid = threadIdx.x;
    int w = tid >> 6, l = tid & 63;
    int h = l >> 5;
    int p   = w >> 1;                           // pair (q-subtile)
    int par = w & 1;                            // KV parity
    int qw  = pt * 2 + p;                       // q-tile-32 index 0..63

    const u16* khb = kh + (size_t)b * 64 * 16 * 512;
    const u16* klb = kl + (size_t)b * 64 * 16 * 512;
    const u16* vwb = vw + (size_t)b * 64 * 8 * 512;

    int kbase = par * 16384;
    int vbase = 32768 + par * 4096;

    auto stageK = [&](int mc) {                 // 32 frags / 2 same-parity waves
        size_t ko = (size_t)mc * 16 * 512;
        #pragma unroll
        for (int i = 0; i < 16; ++i) {
            int g = p * 16 + i;                 // cc = g>>1, hl = g&1
            const u16* src = ((g & 1) ? klb : khb) + ko + (size_t)(g >> 1) * 512 + l * 8;
            gl_lds16(src, &smem[kbase + g * 512]);
        }
    };
    auto stageVW = [&](int mc) {                // 8 frags / 2 waves
        size_t vo = (size_t)mc * 8 * 512;
        #pragma unroll
        for (int i = 0; i < 4; ++i) {
            int f = p * 4 + i;
            gl_lds16(vwb + vo + (size_t)f * 512 + l * 8, &smem[vbase + f * 512]);
        }
    };

    // Q fragments (hi/lo), 16 c-chunks of 16
    short8 qfh[16], qfl[16];
    #pragma unroll
    for (int cc = 0; cc < 16; ++cc) {
        size_t o = (((size_t)b * 64 + qw) * 16 + cc) * 512 + (size_t)l * 8;
        qfh[cc] = *(const short8*)(qh + o);
        qfl[cc] = *(const short8*)(ql + o);
    }

    f32x16 O0 = z16(), O1 = z16(), O2 = z16(), O3 = z16();
    float mrow = -1e30f, lrow = 0.f;

    // prologue: each parity stages its first tile
    stageK(par);
    stageVW(par);
    asm volatile("s_waitcnt vmcnt(0)" ::: "memory");
    __syncthreads();

    for (int r = 0; r < 32; ++r) {
        int mc = 2 * r + par;

        // ---- S = mfma(K, Q) on own parity buffer (3-pass hi/lo bf16) ----
        const short8* KF = (const short8*)&smem[kbase];
        f32x16 sE = z16(), sO = z16();
        #pragma unroll
        for (int cc = 0; cc < 16; cc += 2) {
            short8 ke_h = KF[(cc * 2 + 0) * 64 + l];
            short8 ke_l = KF[(cc * 2 + 1) * 64 + l];
            short8 ko_h = KF[(cc * 2 + 2) * 64 + l];
            short8 ko_l = KF[(cc * 2 + 3) * 64 + l];
            sE = mfma32(ke_h, qfh[cc], sE);
            sO = mfma32(ko_h, qfh[cc + 1], sO);
            sE = mfma32(ke_h, qfl[cc], sE);
            sO = mfma32(ko_h, qfl[cc + 1], sO);
            sE = mfma32(ke_l, qfh[cc], sE);
            sO = mfma32(ko_l, qfh[cc + 1], sO);
        }
        float s[16];
        #pragma unroll
        for (int r2 = 0; r2 < 16; ++r2) s[r2] = sE[r2] + sO[r2];

        RAW_BARRIER();                          // barA: all QK reads done
        if (r < 31) stageK(mc + 2);

        // ---- in-register online softmax (row q = l&31, halves mirrored) ----
        float mx = s[0];
        #pragma unroll
        for (int r2 = 1; r2 < 16; ++r2) mx = fmaxf(mx, s[r2]);
        mx = fmaxf(mx, __shfl_xor(mx, 32));
        bool need = mx > mrow + 8.f;
        if (__any(need)) {
            float mn = fmaxf(mrow, mx);
            float al = exp2f((mrow - mn) * L2E);
            mrow = mn;
            lrow *= al;
            #pragma unroll
            for (int j = 0; j < 16; ++j) {
                int qp = 8 * (j >> 2) + 4 * h + (j & 3);
                float f = bperm_f(qp, al);
                O0[j] *= f; O1[j] *= f; O2[j] *= f; O3[j] *= f;
            }
        }
        float pv[16], sum = 0.f;
        #pragma unroll
        for (int r2 = 0; r2 < 16; ++r2) {
            pv[r2] = exp2f((s[r2] - mrow) * L2E);
            sum += pv[r2];
        }
        sum += __shfl_xor(sum, 32);
        lrow += sum;

        // ---- pack P to fp16 A-frags ----
        f16x8 pa0, pa1;
        #pragma unroll
        for (int ks = 0; ks < 2; ++ks) {
            u32 L0 = pkrtz(pv[8 * ks + 0], pv[8 * ks + 1]);
            u32 L1 = pkrtz(pv[8 * ks + 2], pv[8 * ks + 3]);
            u32 H0 = pkrtz(pv[8 * ks + 4], pv[8 * ks + 5]);
            u32 H1 = pkrtz(pv[8 * ks + 6], pv[8 * ks + 7]);
            u32 pL0 = (u32)__shfl_xor((int)L0, 32);
            u32 pL1 = (u32)__shfl_xor((int)L1, 32);
            u32 pH0 = (u32)__shfl_xor((int)H0, 32);
            u32 pH1 = (u32)__shfl_xor((int)H1, 32);
            union { u32 w[4]; f16x8 v; } u;
            u.w[0] = h ? pH0 : L0;
            u.w[1] = h ? pH1 : L1;
            u.w[2] = h ? H0 : pL0;
            u.w[3] = h ? H1 : pL1;
            if (ks == 0) pa0 = u.v; else pa1 = u.v;
        }

        // VW(mc) landed? queue = [VW(mc) 4, K(mc+2) 16] -> allow 16
        if (r < 31) { asm volatile("s_waitcnt vmcnt(16)" ::: "memory"); }
        else        { asm volatile("s_waitcnt vmcnt(0)"  ::: "memory"); }

        // ---- O += P · VW (fp16, 8 MFMA 32x32x16) ----
        const f16x8* VWF = (const f16x8*)&smem[vbase];
        O0 = mfma32h(pa0, VWF[0 * 64 + l], O0);
        O1 = mfma32h(pa0, VWF[2 * 64 + l], O1);
        O2 = mfma32h(pa0, VWF[4 * 64 + l], O2);
        O3 = mfma32h(pa0, VWF[6 * 64 + l], O3);
        O0 = mfma32h(pa1, VWF[1 * 64 + l], O0);
        O1 = mfma32h(pa1, VWF[3 * 64 + l], O1);
        O2 = mfma32h(pa1, VWF[5 * 64 + l], O2);
        O3 = mfma32h(pa1, VWF[7 * 64 + l], O3);

        asm volatile("s_waitcnt vmcnt(0)" ::: "memory");   // own K(mc+2) done
        RAW_BARRIER();                          // barB: K(mc+2) published
        if (r < 31) stageVW(mc + 2);            // covered by next QK+softmax
    }

    // ---- split-KV merge (on-chip) + epilogue ----
    __syncthreads();                            // K/VW regions now free scratch
    float* scr = (float*)smem;
    if (par == 1) {                             // odd wave: publish partials
        #pragma unroll
        for (int ot = 0; ot < 4; ++ot) {
            const f32x16& Ov = (ot == 0) ? O0 : (ot == 1) ? O1 : (ot == 2) ? O2 : O3;
            #pragma unroll
            for (int j = 0; j < 16; ++j)
                scr[p * 4096 + (ot * 16 + j) * 64 + l] = Ov[j];
        }
        scr[8192 + p * 128 + l] = mrow;
        scr[8192 + p * 128 + 64 + l] = lrow;
    }
    __syncthreads();
    if (par == 0) {                             // even wave: merge + store
        float m_o = scr[8192 + p * 128 + l];
        float l_o = scr[8192 + p * 128 + 64 + l];
        float mm = fmaxf(mrow, m_o);
        float ae = exp2f((mrow - mm) * L2E);
        float ao = exp2f((m_o - mm) * L2E);
        float inv = 1.f / (ae * lrow + ao * l_o);
        float aev = ae * inv, aov = ao * inv;
        float aer[16], aor[16];
        #pragma unroll
        for (int j = 0; j < 16; ++j) {
            int qp = 8 * (j >> 2) + 4 * h + (j & 3);
            aer[j] = bperm_f(qp, aev);
            aor[j] = bperm_f(qp, aov);
        }
        int n0 = pt * 64 + p * 32;
        #pragma unroll
        for (int ot = 0; ot < 4; ++ot) {
            const f32x16& Ov = (ot == 0) ? O0 : (ot == 1) ? O1 : (ot == 2) ? O2 : O3;
            int o = ot * 32 + (l & 31);
            float sc = sf[o], tb = tf[o];
            #pragma unroll
            for (int g = 0; g < 4; ++g) {
                f32x4 res;
                #pragma unroll
                for (int rr = 0; rr < 4; ++rr) {
                    int j = g * 4 + rr;
                    float oo = scr[p * 4096 + (ot * 16 + j) * 64 + l];
                    float mg = aer[j] * Ov[j] + aor[j] * oo;
                    res[rr] = fmaxf(fmaf(mg, sc, tb), 0.f);
                }
                *(f32x4*)(out + ((size_t)b * COUT + o) * N_ + n0 + 8 * g + 4 * h) = res;
            }
        }
    }
}

// ---------------------------------------------------------------------------
extern "C" void kernel_launch(void* const* d_in, const int* in_sizes, int n_in,
                              void* d_out, int out_size, void* d_ws, size_t ws_size,
                              hipStream_t stream)
{
    const float* x   = (const float*)d_in[0];
    const float* Wq  = (const float*)d_in[1];
    const float* Wk  = (const float*)d_in[2];
    const float* Wv  = (const float*)d_in[3];
    const float* Wf  = (const float*)d_in[4];
    const float* bnq = (const float*)d_in[5];
    const float* bnk = (const float*)d_in[6];
    const float* bnv = (const float*)d_in[7];
    const float* bnf = (const float*)d_in[8];
    float* out = (float*)d_out;

    const size_t NBUF = (size_t)B_ * N_ * C_;   // 8,388,608 u16 per buffer
    u16* qh  = (u16*)d_ws;
    u16* ql  = qh + NBUF;
    u16* kh  = ql + NBUF;
    u16* kl  = kh + NBUF;
    u16* vt  = kl + NBUF;
    u16* vwb = vt + NBUF;               // 16*64*8*512 = 4,194,304 u16
    u16* wfh = vwb + 4194304;
    u16* wfl = wfh + 32768;
    u16* wAh = wfl + 32768;             // 3*16*5*64*8 = 122880 u16
    u16* wAl = wAh + 122880;
    float* sqkv = (float*)(wAl + 122880);
    float* tqkv = sqkv + 768;
    float* sf   = tqkv + 768;
    float* tf   = sf + 128;

    w_prep<<<dim3(76), dim3(256), 0, stream>>>(Wq, Wk, Wv, Wf, bnq, bnk, bnv, bnf,
                                               wAh, wAl, wfh, wfl, sqkv, tqkv, sf, tf);
    qkv_proj<<<dim3(1536), dim3(256), 0, stream>>>(x, wAh, wAl, sqkv, tqkv,
                                                   qh, ql, kh, kl, vt);
    vw_proj<<<dim3(256), dim3(256), 0, stream>>>(vt, wfh, wfl, vwb);
    attn_fwd<<<dim3(512), dim3(256), 0, stream>>>(qh, ql, kh, kl, vwb,
                                                  sf, tf, out);
}